// Round 1
// baseline (57.243 us; speedup 1.0000x reference)
//
#include <hip/hip_runtime.h>
#include <hip/hip_bf16.h>
#include <stdint.h>

// QuantConv1D (binary, K=3, Cin=128, Cout=256, VALID) + bias + BN(inference)
// via XNOR-popcount on bit-packed signs.
//
// Shapes: x[64][2048][128] f32 -> out[64][2046][256] f32
// dot(b,t,co) = sum_{k,cin} sign(x[b,t+k,cin]) * sign(ker[k,cin,co])
//             = 384 - 2*popc( xbits(b,t+k) ^ kbits(k,co) )   (384 = 3*128)
// out = dot*inv + (bias-mean)*inv + beta,  inv = 1/sqrt(var+1e-3)
//     = p*A[co] + C[co],  A = -2*inv, C = (384+bias-mean)*inv + beta

#define B 64
#define T 2048
#define CIN 128
#define COUT 256
#define KW 3
#define TOUT (T - KW + 1)   // 2046
#define TCHUNK 66           // 2046 = 31 * 66
#define CHUNKS 31

// ---- pass 1: pack x signs into 2 u64 per (b,t) row ------------------------
__global__ __launch_bounds__(256) void pack_x_kernel(const float* __restrict__ x,
                                                     uint64_t* __restrict__ xb) {
    // one wave (64 lanes) per row; 4 waves/block
    int row  = (blockIdx.x * 256 + threadIdx.x) >> 6;   // (b*T + t)
    int lane = threadIdx.x & 63;
    const float* r = x + (size_t)row * CIN;
    uint64_t m0 = __ballot(r[lane]      >= 0.0f);   // channels 0..63
    uint64_t m1 = __ballot(r[64 + lane] >= 0.0f);   // channels 64..127
    if (lane == 0) {
        xb[(size_t)row * 2 + 0] = m0;
        xb[(size_t)row * 2 + 1] = m1;
    }
}

// ---- pass 2: pack kernel signs + fold bias/BN affine ----------------------
__global__ __launch_bounds__(256) void pack_w_kernel(const float* __restrict__ ker,
                                                     const float* __restrict__ bias,
                                                     const float* __restrict__ beta,
                                                     const float* __restrict__ mean,
                                                     const float* __restrict__ var,
                                                     uint64_t* __restrict__ kb,
                                                     float* __restrict__ A,
                                                     float* __restrict__ C) {
    int k  = blockIdx.x;     // 0..2
    int co = threadIdx.x;    // 0..255
    uint64_t w0 = 0, w1 = 0;
    #pragma unroll 4
    for (int cin = 0; cin < 64; ++cin) {
        // ker[k][cin][co], lanes (co) consecutive -> coalesced
        if (ker[((size_t)k * CIN + cin)      * COUT + co] >= 0.0f) w0 |= (1ull << cin);
        if (ker[((size_t)k * CIN + 64 + cin) * COUT + co] >= 0.0f) w1 |= (1ull << cin);
    }
    kb[((size_t)k * COUT + co) * 2 + 0] = w0;
    kb[((size_t)k * COUT + co) * 2 + 1] = w1;
    if (k == 0) {
        float inv = 1.0f / sqrtf(var[co] + 1e-3f);
        A[co] = -2.0f * inv;
        C[co] = (384.0f + bias[co] - mean[co]) * inv + beta[co];
    }
}

// ---- pass 3: main popcount conv + affine ----------------------------------
__global__ __launch_bounds__(256) void conv_main_kernel(const uint64_t* __restrict__ xb,
                                                        const uint64_t* __restrict__ kb,
                                                        const float* __restrict__ A,
                                                        const float* __restrict__ C,
                                                        float* __restrict__ out) {
    const int co    = threadIdx.x;          // 0..255
    const int chunk = blockIdx.x;           // 0..B*CHUNKS-1
    const int b     = chunk / CHUNKS;
    const int t0    = (chunk % CHUNKS) * TCHUNK;

    // per-thread kernel bits (12 u32 worth)
    const uint64_t k00 = kb[(0 * COUT + co) * 2 + 0];
    const uint64_t k01 = kb[(0 * COUT + co) * 2 + 1];
    const uint64_t k10 = kb[(1 * COUT + co) * 2 + 0];
    const uint64_t k11 = kb[(1 * COUT + co) * 2 + 1];
    const uint64_t k20 = kb[(2 * COUT + co) * 2 + 0];
    const uint64_t k21 = kb[(2 * COUT + co) * 2 + 1];
    const float a = A[co];
    const float c = C[co];

    // stage (TCHUNK+2) rows of xbits in LDS (block-uniform data)
    __shared__ uint64_t xs[(TCHUNK + 2) * 2];
    {
        const uint64_t* src = xb + ((size_t)b * T + t0) * 2;
        int n = (TCHUNK + 2) * 2;   // 136
        for (int i = threadIdx.x; i < n; i += 256) xs[i] = src[i];
    }
    __syncthreads();

    float* orow = out + ((size_t)b * TOUT + t0) * COUT + co;
    #pragma unroll 2
    for (int t = 0; t < TCHUNK; ++t) {
        uint64_t x0 = xs[t * 2 + 0];
        uint64_t x1 = xs[t * 2 + 1];
        uint64_t x2 = xs[t * 2 + 2];
        uint64_t x3 = xs[t * 2 + 3];
        uint64_t x4 = xs[t * 2 + 4];
        uint64_t x5 = xs[t * 2 + 5];
        int p = __popcll(x0 ^ k00) + __popcll(x1 ^ k01)
              + __popcll(x2 ^ k10) + __popcll(x3 ^ k11)
              + __popcll(x4 ^ k20) + __popcll(x5 ^ k21);
        orow[(size_t)t * COUT] = fmaf((float)p, a, c);
    }
}

extern "C" void kernel_launch(void* const* d_in, const int* in_sizes, int n_in,
                              void* d_out, int out_size, void* d_ws, size_t ws_size,
                              hipStream_t stream) {
    const float* x    = (const float*)d_in[0];
    const float* ker  = (const float*)d_in[1];
    const float* bias = (const float*)d_in[2];
    const float* beta = (const float*)d_in[3];
    const float* mean = (const float*)d_in[4];
    const float* var  = (const float*)d_in[5];
    float* out = (float*)d_out;

    // workspace layout: xbits (2 MB) | kbits (12 KB) | A (1 KB) | C (1 KB)
    uint64_t* xb = (uint64_t*)d_ws;
    uint64_t* kb = xb + (size_t)B * T * 2;
    float*    A  = (float*)(kb + (size_t)KW * COUT * 2);
    float*    C  = A + COUT;

    pack_x_kernel<<<(B * T * 64) / 256, 256, 0, stream>>>(x, xb);
    pack_w_kernel<<<KW, 256, 0, stream>>>(ker, bias, beta, mean, var, kb, A, C);
    conv_main_kernel<<<B * CHUNKS, 256, 0, stream>>>(xb, kb, A, C, out);
}

// Round 2
// 50.596 us; speedup vs baseline: 1.1314x; 1.1314x over previous
//
#include <hip/hip_runtime.h>
#include <hip/hip_bf16.h>
#include <stdint.h>

// QuantConv1D (binary, K=3, Cin=128, Cout=256, VALID) + bias + BN(inference)
// via XNOR-popcount on bit-packed signs.
//
// out(b,t,co) = p*A[co] + C[co], p = popc over 384 xor'd bits,
// A = -2/sqrt(var+eps), C = (384+bias-mean)/sqrt(var+eps) + beta.
//
// R1: fused x-pack into conv kernel (ballot per block, +3% boundary re-read),
//     pack_w parallelized 4x over cin, sliding-window regs (1 LDS b128/output).

#define B 64
#define T 2048
#define CIN 128
#define COUT 256
#define KW 3
#define TOUT (T - KW + 1)   // 2046
#define TCHUNK 66           // 2046 = 31 * 66
#define CHUNKS 31
#define NROWS (TCHUNK + KW - 1)  // 68 x-rows per block

// ---- pass 1: pack kernel signs (k x cin-quarter parallel) + fold affine ----
// kb32[(k*4+q)*COUT + co] holds cin bits q*32..q*32+31 for (k, co).
__global__ __launch_bounds__(256) void pack_w_kernel(const float* __restrict__ ker,
                                                     const float* __restrict__ bias,
                                                     const float* __restrict__ beta,
                                                     const float* __restrict__ mean,
                                                     const float* __restrict__ var,
                                                     uint32_t* __restrict__ kb32,
                                                     float* __restrict__ A,
                                                     float* __restrict__ C) {
    int k  = blockIdx.x >> 2;       // 0..2
    int q  = blockIdx.x & 3;        // cin quarter 0..3
    int co = threadIdx.x;           // 0..255
    uint32_t w = 0;
    const float* src = ker + ((size_t)k * CIN + q * 32) * COUT + co;
    #pragma unroll 8
    for (int i = 0; i < 32; ++i) {
        if (src[(size_t)i * COUT] >= 0.0f) w |= (1u << i);
    }
    kb32[(size_t)(k * 4 + q) * COUT + co] = w;
    if (k == 0 && q == 0) {
        float inv = 1.0f / sqrtf(var[co] + 1e-3f);
        A[co] = -2.0f * inv;
        C[co] = (384.0f + bias[co] - mean[co]) * inv + beta[co];
    }
}

// ---- pass 2: fused pack-x + popcount conv + affine ------------------------
__global__ __launch_bounds__(256) void conv_fused_kernel(const float* __restrict__ x,
                                                         const uint32_t* __restrict__ kb32,
                                                         const float* __restrict__ A,
                                                         const float* __restrict__ C,
                                                         float* __restrict__ out) {
    const int co    = threadIdx.x;          // 0..255
    const int chunk = blockIdx.x;           // 0..B*CHUNKS-1
    const int b     = chunk / CHUNKS;
    const int t0    = (chunk % CHUNKS) * TCHUNK;

    __shared__ __align__(16) ulonglong2 xs[NROWS];

    // --- pack NROWS x-rows into LDS via ballot: wave w handles rows w*17.. ---
    {
        const int wid  = threadIdx.x >> 6;
        const int lane = threadIdx.x & 63;
        const float* xrow = x + ((size_t)b * T + t0) * CIN;
        #pragma unroll 4
        for (int i = 0; i < NROWS / 4; ++i) {   // 17 rows per wave
            int r = wid * (NROWS / 4) + i;
            float v0 = xrow[(size_t)r * CIN + lane];
            float v1 = xrow[(size_t)r * CIN + 64 + lane];
            uint64_t m0 = __ballot(v0 >= 0.0f);
            uint64_t m1 = __ballot(v1 >= 0.0f);
            if (lane == 0) { xs[r].x = m0; xs[r].y = m1; }
        }
    }

    // --- per-thread kernel bits + affine ---
    const uint32_t* kc = kb32 + co;
    uint64_t k00 = (uint64_t)kc[0 * COUT] | ((uint64_t)kc[1 * COUT] << 32);
    uint64_t k01 = (uint64_t)kc[2 * COUT] | ((uint64_t)kc[3 * COUT] << 32);
    uint64_t k10 = (uint64_t)kc[4 * COUT] | ((uint64_t)kc[5 * COUT] << 32);
    uint64_t k11 = (uint64_t)kc[6 * COUT] | ((uint64_t)kc[7 * COUT] << 32);
    uint64_t k20 = (uint64_t)kc[8 * COUT] | ((uint64_t)kc[9 * COUT] << 32);
    uint64_t k21 = (uint64_t)kc[10 * COUT] | ((uint64_t)kc[11 * COUT] << 32);
    const float a = A[co];
    const float c = C[co];

    __syncthreads();

    // --- sliding-window popcount conv: 2 outputs / iter, 2 new rows / iter ---
    float* orow = out + ((size_t)b * TOUT + t0) * COUT + co;
    ulonglong2 r0 = xs[0];
    ulonglong2 r1 = xs[1];
    #pragma unroll 3
    for (int t = 0; t < TCHUNK; t += 2) {
        ulonglong2 r2 = xs[t + 2];
        ulonglong2 r3 = xs[t + 3];
        int p0 = __popcll(r0.x ^ k00) + __popcll(r0.y ^ k01)
               + __popcll(r1.x ^ k10) + __popcll(r1.y ^ k11)
               + __popcll(r2.x ^ k20) + __popcll(r2.y ^ k21);
        int p1 = __popcll(r1.x ^ k00) + __popcll(r1.y ^ k01)
               + __popcll(r2.x ^ k10) + __popcll(r2.y ^ k11)
               + __popcll(r3.x ^ k20) + __popcll(r3.y ^ k21);
        orow[(size_t)t * COUT]       = fmaf((float)p0, a, c);
        orow[(size_t)(t + 1) * COUT] = fmaf((float)p1, a, c);
        r0 = r2;
        r1 = r3;
    }
}

extern "C" void kernel_launch(void* const* d_in, const int* in_sizes, int n_in,
                              void* d_out, int out_size, void* d_ws, size_t ws_size,
                              hipStream_t stream) {
    const float* x    = (const float*)d_in[0];
    const float* ker  = (const float*)d_in[1];
    const float* bias = (const float*)d_in[2];
    const float* beta = (const float*)d_in[3];
    const float* mean = (const float*)d_in[4];
    const float* var  = (const float*)d_in[5];
    float* out = (float*)d_out;

    // workspace: kb32 (12 KB) | A (1 KB) | C (1 KB)
    uint32_t* kb32 = (uint32_t*)d_ws;
    float*    A    = (float*)(kb32 + (size_t)KW * 4 * COUT);
    float*    C    = A + COUT;

    pack_w_kernel<<<KW * 4, 256, 0, stream>>>(ker, bias, beta, mean, var, kb32, A, C);
    conv_fused_kernel<<<B * CHUNKS, 256, 0, stream>>>(x, kb32, A, C, out);
}